// Round 9
// baseline (334.778 us; speedup 1.0000x reference)
//
#include <hip/hip_runtime.h>

// SmartDerivatives: out[b, a*3+dim] = (segment_sum(left * x[b,des]))^2
// Deterministic triu_indices(100,1) scatter; index arrays never read.
//
// R9: R5-R8 all ~55-60us kernel regardless of compute structure. Remaining
// theory: stage->barrier->compute phase LOCKSTEP across the 2 resident
// blocks/CU -> HBM duty cycle ~stage/(stage+compute) ~50% (142MB/55us =
// 2.6 TB/s vs 6.3 achievable). Fix: 4 quarter-frame blocks (512thr, 38.6KB
// LDS) -> 4 blocks/CU, finer + unequal chunks desync phases. Compute (fused
// z=left*x at staging, serial register accumulation, zero atomics) unchanged.

#define N_ATOMS 100
#define D_DESC  4950
#define BATCH   1024
#define NOUT    300
#define SZ4_MAX 1964     // max per-chunk float4 count (chunk 1)

// chunk row ranges [r0,r1) and descriptor/f4 ranges (rowstart(i)=i*(199-i)/2)
__constant__ int c_r0[4]  = {0, 14, 31, 53};
__constant__ int c_r1[4]  = {14, 31, 53, 99};
__constant__ int c_f40[4] = {0, 1942, 3906, 5803};   // floor(rowstart(r0)*6/4)
__constant__ int c_f41[4] = {1943, 3906, 5804, 7425};// ceil (rowstart(r1)*6/4)

__device__ __forceinline__ int rowstart(int i) { return (i * (199 - i)) >> 1; }

__global__ __launch_bounds__(512, 8)
void sd_partial_kernel(const float* __restrict__ x,
                       const float* __restrict__ left,
                       float* __restrict__ ws) {
    __shared__ float4 sz4[SZ4_MAX];       // z = left*x chunk, dense-staged
    __shared__ float  spart[NOUT][6];     // [output][3 row + 3 col partials]

    const int b     = blockIdx.x >> 2;
    const int chunk = blockIdx.x & 3;
    const int tid   = threadIdx.x;

    const int r0      = c_r0[chunk];
    const int r1      = c_r1[chunk];
    const int f4start = c_f40[chunk];
    const int f4cnt   = c_f41[chunk] - f4start;
    const int zb      = f4start * 4;      // frame-float offset of sz4[0]

    for (int t = tid; t < NOUT * 6; t += 512) ((float*)spart)[t] = 0.0f;

    const float4* __restrict__ lb4 =
        (const float4*)(left + (size_t)b * (D_DESC * 6)) + f4start;
    const float* __restrict__ xb = x + (size_t)b * D_DESC;

    // ---- stage z: dense float4 left-loads, fused multiply by x (L1/L2-hot).
    // float4 idx covers frame floats g..g+3; g always even -> r=g%6 in
    // {0,2,4}; only r==4 straddles two descriptors (elements 2,3 -> d0+1).
    #pragma unroll
    for (int k = 0; k < 4; ++k) {
        const int idx = tid + k * 512;
        if (idx < f4cnt) {
            const float4 L = lb4[idx];
            const int g  = (f4start + idx) * 4;
            const int d0 = g / 6;
            const int r  = g - 6 * d0;
            const float x0 = xb[d0];
            const float x1 = xb[(g + 3) / 6];   // == x0 unless r==4
            float4 z;
            z.x = L.x * x0;
            z.y = L.y * x0;
            z.z = L.z * ((r + 2 >= 6) ? x1 : x0);
            z.w = L.w * ((r + 3 >= 6) ? x1 : x0);
            sz4[idx] = z;
        }
    }
    __syncthreads();

    const float* __restrict__ sz = (const float*)sz4;
    const int nr = r1 - r0;

    // ---- row part: thread (a,q), a in chunk rows: sum channels 0..2
    if (tid < 3 * nr) {
        const int a   = r0 + tid / 3;
        const int q   = tid - 3 * (tid / 3);
        const int rs  = rowstart(a);
        const int len = 99 - a;
        const float* __restrict__ base = sz + (rs * 6 - zb);
        float s0 = 0.f, s1 = 0.f, s2 = 0.f;
        for (int m = q; m < len; m += 3) {
            const float2 c01 = *(const float2*)(base + m * 6);  // 8B-aligned
            const float  c2  = base[m * 6 + 2];
            s0 += c01.x; s1 += c01.y; s2 += c2;
        }
        spart[a * 3 + 0][q] = s0;
        spart[a * 3 + 1][q] = s1;
        spart[a * 3 + 2][q] = s2;
    }

    // ---- col part: thread (j,q), j in (r0,99]: sum channels 3..5 over
    // rows i in [r0+q, min(j,r1)) step 3; d(i,j)=rowstart(i)+j-i-1 incremental
    const int cbase = 3 * nr;
    const int nc    = 99 - r0;
    const int t2    = tid - cbase;
    if (t2 >= 0 && t2 < 3 * nc) {
        const int j = r0 + 1 + t2 / 3;
        const int q = t2 - 3 * (t2 / 3);
        float s3 = 0.f, s4 = 0.f, s5 = 0.f;
        int i = r0 + q;
        const int iend = (j < r1) ? j : r1;
        if (i < iend) {
            int d    = rowstart(i) + j - i - 1;
            int step = 291 - 3 * i;            // d(i+3,j) - d(i,j)
            while (true) {
                const int f = d * 6 + 3 - zb;
                s3 += sz[f]; s4 += sz[f + 1]; s5 += sz[f + 2];
                i += 3;
                if (i >= iend) break;
                d += step; step -= 9;
            }
        }
        spart[j * 3 + 0][3 + q] = s3;
        spart[j * 3 + 1][3 + q] = s4;
        spart[j * 3 + 2][3 + q] = s5;
    }
    __syncthreads();

    // ---- combine 6 partials per output, write to ws[chunk][b][o]
    if (tid < NOUT) {
        const float* p = spart[tid];
        ws[((size_t)chunk * BATCH + b) * NOUT + tid] =
            p[0] + p[1] + p[2] + p[3] + p[4] + p[5];
    }
}

// out = (ws0+ws1+ws2+ws3)^2, float4-vectorized. 76800 float4s / 256 = 300.
__global__ __launch_bounds__(256)
void sd_combine_kernel(const float* __restrict__ ws, float* __restrict__ out) {
    const int idx = blockIdx.x * 256 + threadIdx.x;
    const size_t stride = (size_t)BATCH * NOUT;
    const float4 u0 = ((const float4*)ws)[idx];
    const float4 u1 = ((const float4*)(ws + stride))[idx];
    const float4 u2 = ((const float4*)(ws + 2 * stride))[idx];
    const float4 u3 = ((const float4*)(ws + 3 * stride))[idx];
    float4 o;
    o.x = u0.x + u1.x + u2.x + u3.x; o.x *= o.x;
    o.y = u0.y + u1.y + u2.y + u3.y; o.y *= o.y;
    o.z = u0.z + u1.z + u2.z + u3.z; o.z *= o.z;
    o.w = u0.w + u1.w + u2.w + u3.w; o.w *= o.w;
    ((float4*)out)[idx] = o;
}

extern "C" void kernel_launch(void* const* d_in, const int* in_sizes, int n_in,
                              void* d_out, int out_size, void* d_ws, size_t ws_size,
                              hipStream_t stream) {
    const float* x    = (const float*)d_in[0];   // [BATCH, D]
    const float* left = (const float*)d_in[1];   // [BATCH*D*6]
    float* ws  = (float*)d_ws;                   // 4*1024*300 floats = 4.9 MB
    float* out = (float*)d_out;                  // [BATCH, 300]

    sd_partial_kernel<<<BATCH * 4, 512, 0, stream>>>(x, left, ws);
    sd_combine_kernel<<<(BATCH * NOUT / 4) / 256, 256, 0, stream>>>(ws, out);
}